// Round 7
// baseline (202.325 us; speedup 1.0000x reference)
//
#include <hip/hip_runtime.h>

typedef __bf16 bf16;
typedef __bf16 bf16x4 __attribute__((ext_vector_type(4)));
typedef __bf16 bf16x8 __attribute__((ext_vector_type(8)));
typedef float f32x4 __attribute__((ext_vector_type(4)));

#define D_MODEL 1024
#define PROJ    256
#define SEQ     2048
#define BATCH   2
#define TOK     4096   // BATCH*SEQ
#define NH      16
#define DH      64
#define NEG_BIG (-1e30f)
#define QSCALE  0.18033688011112042f   // 0.125 * log2(e), folded into Qh

#if __has_builtin(__builtin_amdgcn_exp2f)
#define EXP2(x) __builtin_amdgcn_exp2f(x)
#else
#define EXP2(x) exp2f(x)
#endif

typedef __attribute__((address_space(3))) unsigned int  lds_u32;
typedef __attribute__((address_space(1))) unsigned int  glb_u32;

// async 16B/lane global->LDS (gfx950 global_load_lds_dwordx4).
__device__ __forceinline__ void gl2lds16(const void* gsrc, void* ldst) {
    __builtin_amdgcn_global_load_lds((const glb_u32*)gsrc, (lds_u32*)ldst, 16, 0, 0);
}

// counted waits (T4): never drain vmcnt to 0 inside the main loop.
#define VM_WAIT(N) asm volatile("s_waitcnt vmcnt(" #N ")" ::: "memory")
#define SCHEDB()   __builtin_amdgcn_sched_barrier(0)
#define SBAR()     __builtin_amdgcn_s_barrier()

// ---------------------------------------------------------------------------
// DPP 16-lane row sum (groups are contiguous 16-lane DPP rows).
template <int CTRL>
__device__ __forceinline__ float dppmov(float x) {
    int i = __builtin_bit_cast(int, x);
    i = __builtin_amdgcn_update_dpp(i, i, CTRL, 0xf, 0xf, false);
    return __builtin_bit_cast(float, i);
}
__device__ __forceinline__ float rowsum16(float v) {
    v += dppmov<0xB1>(v);
    v += dppmov<0x4E>(v);
    v += dppmov<0x141>(v);
    v += dppmov<0x140>(v);
    return v;
}

// ---------------------------------------------------------------------------
// Merged prep: blocks [0,320) LDS-tiled weight transposes; rest float4 copy.
__global__ __launch_bounds__(256) void prep_kernel(
    const float* __restrict__ W_o, const float* __restrict__ x,
    const float* __restrict__ W_dq, const float* __restrict__ W_dkv,
    const float* __restrict__ W_uq, const float* __restrict__ W_ukv,
    bf16* __restrict__ Wo16, bf16* __restrict__ x16,
    bf16* __restrict__ Wt_dq, bf16* __restrict__ Wt_dkv,
    bf16* __restrict__ Wt_uq, bf16* __restrict__ Wt_ukv) {
    if (blockIdx.x < 320) {
        __shared__ float tile[64][65];   // +1 pad: conflict-free transposed reads
        int t = blockIdx.x;
        const float* src; bf16* dst; int R, C;
        if (t < 64)       { src = W_dq;  dst = Wt_dq;  R = 1024; C = 256; }
        else if (t < 128) { src = W_dkv; dst = Wt_dkv; R = 1024; C = 256;  t -= 64; }
        else if (t < 192) { src = W_uq;  dst = Wt_uq;  R = 256;  C = 1024; t -= 128; }
        else              { src = W_ukv; dst = Wt_ukv; R = 256;  C = 2048; t -= 192; }
        const int tilesC = C >> 6;
        const int r0 = (t / tilesC) << 6;
        const int c0 = (t % tilesC) << 6;
        const int tr = threadIdx.x >> 6;   // 0..3
        const int tc = threadIdx.x & 63;
#pragma unroll
        for (int i = 0; i < 16; ++i)
            tile[tr * 16 + i][tc] = src[(size_t)(r0 + tr * 16 + i) * C + c0 + tc];
        __syncthreads();
#pragma unroll
        for (int i = 0; i < 16; ++i)
            dst[(size_t)(c0 + tr * 16 + i) * R + r0 + tc] =
                (bf16)tile[tc][tr * 16 + i];
    } else {
        const int NW = 262144;    // W_o float4 count
        const int NX = 1048576;   // x float4 count
        for (int i = (blockIdx.x - 320) * 256 + threadIdx.x; i < NW + NX;
             i += 1024 * 256) {
            if (i < NW) {
                float4 v = ((const float4*)W_o)[i];
                bf16x4 p;
                p[0] = (bf16)v.x; p[1] = (bf16)v.y;
                p[2] = (bf16)v.z; p[3] = (bf16)v.w;
                ((bf16x4*)Wo16)[i] = p;
            } else {
                int j = i - NW;
                float4 v = ((const float4*)x)[j];
                bf16x4 p;
                p[0] = (bf16)v.x; p[1] = (bf16)v.y;
                p[2] = (bf16)v.z; p[3] = (bf16)v.w;
                ((bf16x4*)x16)[j] = p;
            }
        }
    }
}

// ---------------------------------------------------------------------------
// Dual LN-GEMM. BM=16, N=256, BK=32. 3-buffer, 1 barrier/step, counted vmcnt.
__global__ __launch_bounds__(256) void gemm_ln_kernel(
    const bf16* __restrict__ x16,
    const bf16* __restrict__ Wt_q, const bf16* __restrict__ Wt_kv,
    const float* __restrict__ q_g, const float* __restrict__ q_b,
    const float* __restrict__ kv_g, const float* __restrict__ kv_b,
    bf16* __restrict__ cq, bf16* __restrict__ ckv) {
    __shared__ alignas(16) bf16 xA[3][16 * 32];     // 3 x 1 KB
    __shared__ alignas(16) bf16 wB[3][256 * 32];    // 3 x 16 KB
    __shared__ float red1[4][16];
    __shared__ float red2[4][16];

    const int K = 1024;
    const bf16* Wt = blockIdx.y ? Wt_kv : Wt_q;
    const float* gamma = blockIdx.y ? kv_g : q_g;
    const float* beta  = blockIdx.y ? kv_b : q_b;
    bf16* out = blockIdx.y ? ckv : cq;

    const int m0 = blockIdx.x * 16;
    const int wv = threadIdx.x >> 6;
    const int lane = threadIdx.x & 63;
    const int g = lane >> 4;
    const int ln16 = lane & 15;

    const int crow = lane >> 2;
    const int ckc = lane & 3;
    const bf16* gx = x16 + (size_t)(m0 + crow) * K + ckc * 8;
    const bf16* gw = Wt + (size_t)(64 * wv + crow) * K + ckc * 8;

    f32x4 acc[4] = {};
    const int nst = K >> 5;          // 32 steps

    // prologue: stage steps 0,1 (x staged redundantly by all waves: uniform
    // per-wave load counts; identical bytes -> benign duplicate LDS writes)
#pragma unroll
    for (int s = 0; s < 2; ++s) {
        gl2lds16(gx + s * 32, (char*)xA + s * 1024);
#pragma unroll
        for (int i = 0; i < 4; ++i)
            gl2lds16(gw + (size_t)i * 16 * K + s * 32,
                     (char*)wB + s * 16384 + wv * 4096 + i * 1024);
    }
    VM_WAIT(0); SCHEDB(); SBAR();

    for (int s = 0; s < nst; ++s) {
        if (s > 0) {
            if (s + 1 < nst) { VM_WAIT(5); } else { VM_WAIT(0); }
            SCHEDB(); SBAR();
        }
        if (s + 2 < nst) {
            const int b3 = (s + 2) % 3;
            const int k2 = (s + 2) * 32;
            gl2lds16(gx + k2, (char*)xA + b3 * 1024);
#pragma unroll
            for (int i = 0; i < 4; ++i)
                gl2lds16(gw + (size_t)i * 16 * K + k2,
                         (char*)wB + b3 * 16384 + wv * 4096 + i * 1024);
        }
        const bf16* cx = &xA[s % 3][0];
        const bf16* cw = &wB[s % 3][0];
        bf16x8 a = *(const bf16x8*)(cx + ln16 * 32 + g * 8);
        bf16x8 bb[4];
#pragma unroll
        for (int t = 0; t < 4; ++t)
            bb[t] = *(const bf16x8*)(cw + (wv * 64 + 16 * t + ln16) * 32 + g * 8);
        __builtin_amdgcn_s_setprio(1);
#pragma unroll
        for (int t = 0; t < 4; ++t)
            acc[t] = __builtin_amdgcn_mfma_f32_16x16x32_bf16(a, bb[t], acc[t], 0, 0, 0);
        __builtin_amdgcn_s_setprio(0);
    }

    // lane holds C rows m0+4g+r, cols 64wv+16t+ln16
    float s1[4], s2[4];
#pragma unroll
    for (int r = 0; r < 4; ++r) {
        float a = 0.f, b = 0.f;
#pragma unroll
        for (int t = 0; t < 4; ++t) { float v = acc[t][r]; a += v; b += v * v; }
        s1[r] = rowsum16(a); s2[r] = rowsum16(b);
    }
    if (ln16 == 0) {
#pragma unroll
        for (int r = 0; r < 4; ++r) {
            red1[wv][g * 4 + r] = s1[r];
            red2[wv][g * 4 + r] = s2[r];
        }
    }
    __syncthreads();
#pragma unroll
    for (int r = 0; r < 4; ++r) {
        int rl = g * 4 + r;
        float t1 = red1[0][rl] + red1[1][rl] + red1[2][rl] + red1[3][rl];
        float t2 = red2[0][rl] + red2[1][rl] + red2[2][rl] + red2[3][rl];
        float mu = t1 * (1.0f / 256.0f);
        float var = t2 * (1.0f / 256.0f) - mu * mu;
        float rs = rsqrtf(var + 1e-5f);
        int row = m0 + rl;
#pragma unroll
        for (int t = 0; t < 4; ++t) {
            int col = wv * 64 + 16 * t + ln16;
            float v = (acc[t][r] - mu) * rs * gamma[col] + beta[col];
            out[(size_t)row * PROJ + col] = (bf16)v;
        }
    }
}

// ---------------------------------------------------------------------------
// 128x128 GEMM body, BK=32, 4 waves. 3-buffer, 1 barrier/step.
__device__ __forceinline__ void gemm_body128(
    const bf16* __restrict__ A, const bf16* __restrict__ Bt,
    bf16* __restrict__ C, bf16* __restrict__ C2, int K,
    int bx, int by, int mode, bf16* tA, bf16* tB) {
    // tA,tB: [3][128*32] bf16 (3 x 8 KB each)
    const int w = threadIdx.x >> 6;
    const int lane = threadIdx.x & 63;
    const int g = lane >> 4;
    const int ln16 = lane & 15;
    const int wr = w >> 1;
    const int wc = w & 1;

    const int m0 = bx * 128;
    const int n0 = by * 128;

    const int crow = lane >> 2;
    const int ckc = lane & 3;
    const bf16* gA0 = A  + (size_t)(m0 + 32 * w + crow) * K + ckc * 8;
    const bf16* gA1 = gA0 + (size_t)16 * K;
    const bf16* gB0 = Bt + (size_t)(n0 + 32 * w + crow) * K + ckc * 8;
    const bf16* gB1 = gB0 + (size_t)16 * K;

    f32x4 acc[4][4] = {};
    const int nst = K >> 5;

    // prologue: stage steps 0,1
#pragma unroll
    for (int s = 0; s < 2; ++s) {
        gl2lds16(gA0 + s * 32, (char*)tA + s * 8192 + w * 2048);
        gl2lds16(gA1 + s * 32, (char*)tA + s * 8192 + w * 2048 + 1024);
        gl2lds16(gB0 + s * 32, (char*)tB + s * 8192 + w * 2048);
        gl2lds16(gB1 + s * 32, (char*)tB + s * 8192 + w * 2048 + 1024);
    }
    VM_WAIT(0); SCHEDB(); SBAR();

    for (int s = 0; s < nst; ++s) {
        if (s > 0) {
            if (s + 1 < nst) { VM_WAIT(4); } else { VM_WAIT(0); }
            SCHEDB(); SBAR();
        }
        if (s + 2 < nst) {
            const int b3 = (s + 2) % 3;
            const int k2 = (s + 2) * 32;
            gl2lds16(gA0 + k2, (char*)tA + b3 * 8192 + w * 2048);
            gl2lds16(gA1 + k2, (char*)tA + b3 * 8192 + w * 2048 + 1024);
            gl2lds16(gB0 + k2, (char*)tB + b3 * 8192 + w * 2048);
            gl2lds16(gB1 + k2, (char*)tB + b3 * 8192 + w * 2048 + 1024);
        }
        const bf16* cA = tA + (s % 3) * 4096;   // elements
        const bf16* cB = tB + (s % 3) * 4096;

        bf16x8 af[4], bfr[4];
#pragma unroll
        for (int q = 0; q < 4; ++q)
            af[q] = *(const bf16x8*)(cA + (wr * 64 + q * 16 + ln16) * 32 + g * 8);
#pragma unroll
        for (int t = 0; t < 4; ++t)
            bfr[t] = *(const bf16x8*)(cB + (wc * 64 + t * 16 + ln16) * 32 + g * 8);
        __builtin_amdgcn_s_setprio(1);
#pragma unroll
        for (int q = 0; q < 4; ++q)
#pragma unroll
            for (int t = 0; t < 4; ++t)
                acc[q][t] = __builtin_amdgcn_mfma_f32_16x16x32_bf16(
                    af[q], bfr[t], acc[q][t], 0, 0, 0);
        __builtin_amdgcn_s_setprio(0);
    }

#pragma unroll
    for (int q = 0; q < 4; ++q)
#pragma unroll
        for (int t = 0; t < 4; ++t) {
            const int col = n0 + wc * 64 + t * 16 + ln16;
            const int tok0 = m0 + wr * 64 + q * 16 + g * 4;
            if (mode == 2 && col >= 1024) {
                int cc = col - 1024;
                int h = cc >> 6, d = cc & 63;
                int b = tok0 >> 11, sq = tok0 & 2047;
                bf16x4 pk;
#pragma unroll
                for (int r = 0; r < 4; ++r) pk[r] = (bf16)acc[q][t][r];
                *(bf16x4*)(C2 + ((size_t)((b * 16 + h) * 64 + d) * SEQ + sq)) = pk;
            } else {
#pragma unroll
                for (int r = 0; r < 4; ++r) {
                    int row = tok0 + r;
                    float v = acc[q][t][r];
                    if (mode == 1) v *= QSCALE;
                    int h = col >> 6, d = col & 63;
                    int b = row >> 11, sq = row & 2047;
                    C[((size_t)((b * 16 + h) * 2048 + sq)) * 64 + d] = (bf16)v;
                }
            }
        }
}

// Merged Q-proj + KV-proj: blocks [0,256) = Q (32x8), [256,768) = KV (32x16).
__global__ __launch_bounds__(256) void gemm_qkv_kernel(
    const bf16* __restrict__ cq, const bf16* __restrict__ Wt_uq,
    const bf16* __restrict__ ckv, const bf16* __restrict__ Wt_ukv,
    bf16* __restrict__ Qh, bf16* __restrict__ Kh, bf16* __restrict__ Vt) {
    __shared__ alignas(16) bf16 tA[3][128 * 32];
    __shared__ alignas(16) bf16 tB[3][128 * 32];
    const int i = blockIdx.x;
    if (i < 256) {
        gemm_body128(cq, Wt_uq, Qh, nullptr, PROJ,
                     i >> 3, i & 7, 1, &tA[0][0], &tB[0][0]);
    } else {
        const int j = i - 256;
        gemm_body128(ckv, Wt_ukv, Kh, Vt, PROJ,
                     j >> 4, j & 15, 2, &tA[0][0], &tB[0][0]);
    }
}

// ---------------------------------------------------------------------------
// 64x128 GEMM body, BK=32, 4 waves. 3-buffer, 1 barrier/step.
__device__ __forceinline__ void gemm_body(
    const bf16* __restrict__ A, const bf16* __restrict__ Bt,
    float* __restrict__ C, int N, int K,
    int bx, int by, bf16* tA, bf16* tB) {
    const int w = threadIdx.x >> 6;
    const int lane = threadIdx.x & 63;
    const int g = lane >> 4;
    const int ln16 = lane & 15;
    const int wr = w >> 1;
    const int wc = w & 1;

    const int m0 = bx * 64;
    const int n0 = by * 128;

    const int crow = lane >> 2;
    const int ckc = lane & 3;
    const bf16* gA  = A  + (size_t)(m0 + w * 16 + crow) * K + ckc * 8;
    const bf16* gB0 = Bt + (size_t)(n0 + w * 16 + crow) * K + ckc * 8;
    const bf16* gB1 = Bt + (size_t)(n0 + 64 + w * 16 + crow) * K + ckc * 8;

    f32x4 acc[2][4] = {};
    const int nst = K >> 5;

    // prologue: stage steps 0,1
#pragma unroll
    for (int s = 0; s < 2; ++s) {
        gl2lds16(gA + s * 32, (char*)tA + s * 4096 + w * 1024);
        gl2lds16(gB0 + s * 32, (char*)tB + s * 8192 + w * 1024);
        gl2lds16(gB1 + s * 32, (char*)tB + s * 8192 + 4096 + w * 1024);
    }
    VM_WAIT(0); SCHEDB(); SBAR();

    for (int s = 0; s < nst; ++s) {
        if (s > 0) {
            if (s + 1 < nst) { VM_WAIT(3); } else { VM_WAIT(0); }
            SCHEDB(); SBAR();
        }
        if (s + 2 < nst) {
            const int b3 = (s + 2) % 3;
            const int k2 = (s + 2) * 32;
            gl2lds16(gA + k2, (char*)tA + b3 * 4096 + w * 1024);
            gl2lds16(gB0 + k2, (char*)tB + b3 * 8192 + w * 1024);
            gl2lds16(gB1 + k2, (char*)tB + b3 * 8192 + 4096 + w * 1024);
        }
        const bf16* cA = tA + (s % 3) * 2048;   // elements
        const bf16* cB = tB + (s % 3) * 4096;

        bf16x8 af[2], bfr[4];
#pragma unroll
        for (int q = 0; q < 2; ++q)
            af[q] = *(const bf16x8*)(cA + (wr * 32 + q * 16 + ln16) * 32 + g * 8);
#pragma unroll
        for (int t = 0; t < 4; ++t)
            bfr[t] = *(const bf16x8*)(cB + (wc * 64 + t * 16 + ln16) * 32 + g * 8);
        __builtin_amdgcn_s_setprio(1);
#pragma unroll
        for (int q = 0; q < 2; ++q)
#pragma unroll
            for (int t = 0; t < 4; ++t)
                acc[q][t] = __builtin_amdgcn_mfma_f32_16x16x32_bf16(
                    af[q], bfr[t], acc[q][t], 0, 0, 0);
        __builtin_amdgcn_s_setprio(0);
    }

#pragma unroll
    for (int q = 0; q < 2; ++q)
#pragma unroll
        for (int t = 0; t < 4; ++t) {
            const int col = n0 + wc * 64 + t * 16 + ln16;
            const int tok0 = m0 + wr * 32 + q * 16 + g * 4;
#pragma unroll
            for (int r = 0; r < 4; ++r)
                C[(size_t)(tok0 + r) * N + col] = acc[q][t][r];
        }
}

// O-projection (fp32 out)
__global__ __launch_bounds__(256) void gemm_o_kernel(
    const bf16* __restrict__ A, const bf16* __restrict__ Bt,
    float* __restrict__ C, int M, int N, int K) {
    __shared__ alignas(16) bf16 tA[3][64 * 32];
    __shared__ alignas(16) bf16 tB[3][128 * 32];
    gemm_body(A, Bt, C, N, K, blockIdx.x, blockIdx.y, &tA[0][0], &tB[0][0]);
}

// ---------------------------------------------------------------------------
// Flash attention v8: r5 geometry (1024 blocks x 128 thr, 2 waves x 32 q-rows,
// 4 blocks/CU, heavy-first backfill), K double-buffered in LDS (16 KB only),
// V fragments read DIRECTLY global->registers (16B/lane contiguous from Vt),
// latency hidden by exact counted vmcnt: per iter issue [8 V][4 K-stage],
// so VM_WAIT(4) before PV leaves exactly the K prefetch in flight (in-order
// vmcnt counting, m135). Branchless prefetch (clamped index). li on MFMA pipe.
__device__ __forceinline__ void qk_exp_pack(
    int k0, int q, bool masked, int g, int ln16,
    bf16x8 aq0, bf16x8 aq1, const bf16x8* Kf,
    bf16x8& P1, bf16x8& P2) {
    f32x4 sc[4];
    __builtin_amdgcn_s_setprio(1);
#pragma unroll
    for (int c = 0; c < 4; ++c) {
        f32x4 z = {};
        z = __builtin_amdgcn_mfma_f32_16x16x32_bf16(Kf[2 * c], aq0, z, 0, 0, 0);
        z = __builtin_amdgcn_mfma_f32_16x16x32_bf16(Kf[2 * c + 1], aq1, z, 0, 0, 0);
        sc[c] = z;
    }
    __builtin_amdgcn_s_setprio(0);
    if (masked) {
        const int kb = k0 + 8 * g;
#pragma unroll
        for (int c = 0; c < 4; ++c)
#pragma unroll
            for (int r = 0; r < 4; ++r) {
                int kcol = kb + (c & 1) * 4 + r + ((c >> 1) << 5);
                if (kcol > q) sc[c][r] = NEG_BIG;
            }
    }
#pragma unroll
    for (int c = 0; c < 4; ++c)
#pragma unroll
        for (int r = 0; r < 4; ++r) sc[c][r] = EXP2(sc[c][r]);
#pragma unroll
    for (int r = 0; r < 4; ++r) {
        P1[r] = (bf16)sc[0][r]; P1[4 + r] = (bf16)sc[1][r];
        P2[r] = (bf16)sc[2][r]; P2[4 + r] = (bf16)sc[3][r];
    }
}

__device__ __forceinline__ void pv_accum(
    bf16x8 P1, bf16x8 P2, const bf16x8* Vf, bf16x8 vones,
    f32x4* o, f32x4& oli) {
    __builtin_amdgcn_s_setprio(1);
#pragma unroll
    for (int t = 0; t < 4; ++t) {
        o[t] = __builtin_amdgcn_mfma_f32_16x16x32_bf16(Vf[2 * t], P1, o[t], 0, 0, 0);
        o[t] = __builtin_amdgcn_mfma_f32_16x16x32_bf16(Vf[2 * t + 1], P2, o[t], 0, 0, 0);
    }
    // li[q] = sum_k P[k][q] on the MFMA pipe (all output rows identical)
    oli = __builtin_amdgcn_mfma_f32_16x16x32_bf16(vones, P1, oli, 0, 0, 0);
    oli = __builtin_amdgcn_mfma_f32_16x16x32_bf16(vones, P2, oli, 0, 0, 0);
    __builtin_amdgcn_s_setprio(0);
}

__global__ __launch_bounds__(128) void attn_kernel(
    const bf16* __restrict__ Qh, const bf16* __restrict__ Kh,
    const bf16* __restrict__ Vt, bf16* __restrict__ AT) {
    __shared__ alignas(128) bf16 kbuf[2][64 * 64];   // [buf][k][d], swizzled, 16 KB

    const int lane = threadIdx.x & 63;
    const int g = lane >> 4;
    const int ln16 = lane & 15;
    const int wv = threadIdx.x >> 6;             // 0..1

    const int bh = blockIdx.x & 31;
    const int qsuper = 31 - (blockIdx.x >> 5);   // heavy-first
    const int nt = qsuper + 1;
    const int qb = qsuper * 64 + wv * 32;        // this wave's 32 q-rows

    const bf16* Kbh = Kh + (size_t)bh * SEQ * DH;
    const bf16* Vbh = Vt + (size_t)bh * DH * SEQ;

    // ---- K staging: wave wv stages rows [32wv, 32wv+32), 4 instrs/tile.
    // Swizzle: chunk c of row r stored at slot c ^ f(r),
    // f(r) = (r&3)|(((r>>3)&1)<<2); applied on the global source address.
    const int rho = lane >> 3;
    const int sl  = lane & 7;
    int kofs[4];
#pragma unroll
    for (int i = 0; i < 4; ++i) {
        const int row = 32 * wv + 8 * i + rho;
        const int c = sl ^ ((rho & 3) | ((i & 1) << 2));  // = sl ^ f(row)
        kofs[i] = row * 64 + c * 8;
    }

    // ---- loop-invariant swizzled K fragment-read byte offsets (within a buf)
    const int row_base = ((ln16 & 12) << 1) + (ln16 & 3);
    int kro[4];
#pragma unroll
    for (int c = 0; c < 4; ++c) {
        const int row = row_base + (c & 1) * 4 + ((c >> 1) << 5);
        const int fr = (row & 3) | (((row >> 3) & 1) << 2);
        kro[c] = row * 128 + (g ^ fr) * 16;
    }

    // ---- V direct-from-global fragment pointers (16B/lane contiguous)
    const bf16* vp[4];
#pragma unroll
    for (int t = 0; t < 4; ++t)
        vp[t] = Vbh + (size_t)(16 * t + ln16) * SEQ + 8 * g;

    // Q fragments for both 16-row halves
    bf16x8 aq[2][2];
#pragma unroll
    for (int hh = 0; hh < 2; ++hh) {
        const bf16* qp = Qh + ((size_t)bh * SEQ + qb + 16 * hh + ln16) * DH + g * 8;
        aq[hh][0] = *(const bf16x8*)qp;
        aq[hh][1] = *(const bf16x8*)(qp + 32);
    }

    bf16x8 vones;
#pragma unroll
    for (int i = 0; i < 8; ++i) vones[i] = (bf16)1.0f;

    f32x4 o0[4] = {}, o1[4] = {};
    f32x4 oli0 = {}, oli1 = {};

    // prologue: stage K tile 0 -> buf0, K tile min(1,nt-1) -> buf1
    {
        const int t1 = (nt > 1) ? 1 : 0;
#pragma unroll
        for (int i = 0; i < 4; ++i) {
            gl2lds16(Kbh + kofs[i], (char*)kbuf + wv * 4096 + i * 1024);
            gl2lds16(Kbh + (size_t)t1 * 64 * 64 + kofs[i],
                     (char*)kbuf + 8192 + wv * 4096 + i * 1024);
        }
    }
    VM_WAIT(0); SCHEDB(); SBAR();

    for (int kt = 0; kt < nt; ++kt) {
        if (kt > 0) { SBAR(); }   // partner's K(kt) stage landed (see proof)
        const char* kb = (const char*)kbuf + (kt & 1) * 8192;
        bf16x8 Kf[8];
#pragma unroll
        for (int c = 0; c < 4; ++c) {
            Kf[2 * c]     = *(const bf16x8*)(kb + kro[c]);
            Kf[2 * c + 1] = *(const bf16x8*)(kb + (kro[c] ^ 64));
        }
        asm volatile("s_waitcnt lgkmcnt(0)" ::: "memory");
        SCHEDB(); SBAR();          // both waves done reading buf[kt&1]

        const int k0 = kt * 64;
        // V fragment loads for this tile (8 plain global_load_dwordx4)
        bf16x8 Vf[8];
        SCHEDB();
#pragma unroll
        for (int t = 0; t < 4; ++t) {
            Vf[2 * t]     = *(const bf16x8*)(vp[t] + k0);
            Vf[2 * t + 1] = *(const bf16x8*)(vp[t] + k0 + 32);
        }
        SCHEDB();
        // K prefetch for tile kt+2 (clamped: branchless, uniform counts)
        {
            const int kt2 = (kt + 2 < nt) ? kt + 2 : nt - 1;
            char* kd = (char*)kbuf + (kt & 1) * 8192 + wv * 4096;
#pragma unroll
            for (int i = 0; i < 4; ++i)
                gl2lds16(Kbh + (size_t)kt2 * 64 * 64 + kofs[i], kd + i * 1024);
        }
        SCHEDB();

        const bool msk = (kt == qsuper);
        bf16x8 P1a, P2a, P1b, P2b;
        qk_exp_pack(k0, qb + ln16, msk, g, ln16,
                    aq[0][0], aq[0][1], Kf, P1a, P2a);
        qk_exp_pack(k0, qb + 16 + ln16, msk, g, ln16,
                    aq[1][0], aq[1][1], Kf, P1b, P2b);

        VM_WAIT(4); SCHEDB();     // V landed; only newest-4 (K prefetch) in flight
        pv_accum(P1a, P2a, Vf, vones, o0, oli0);
        pv_accum(P1b, P2b, Vf, vones, o1, oli1);
    }
    VM_WAIT(0);                   // drain dangling K stages before LDS dealloc

    // epilogue: oli rows all identical = li[q]
    const float inv0 = 1.0f / oli0[0];
    const float inv1 = 1.0f / oli1[0];
    const int b = bh >> 4, h = bh & 15;
    const size_t tok0 = (size_t)(b * SEQ + qb + ln16) * D_MODEL + h * DH;
    const size_t tok1 = (size_t)(b * SEQ + qb + 16 + ln16) * D_MODEL + h * DH;
#pragma unroll
    for (int t = 0; t < 4; ++t) {
        bf16x4 pk0, pk1;
#pragma unroll
        for (int r = 0; r < 4; ++r) {
            pk0[r] = (bf16)(o0[t][r] * inv0);
            pk1[r] = (bf16)(o1[t][r] * inv1);
        }
        *(bf16x4*)(AT + tok0 + 16 * t + 4 * g) = pk0;
        *(bf16x4*)(AT + tok1 + 16 * t + 4 * g) = pk1;
    }
}

// ---------------------------------------------------------------------------
extern "C" void kernel_launch(void* const* d_in, const int* in_sizes, int n_in,
                              void* d_out, int out_size, void* d_ws, size_t ws_size,
                              hipStream_t stream) {
    const float* x     = (const float*)d_in[0];
    const float* W_dq  = (const float*)d_in[1];
    const float* W_uq  = (const float*)d_in[2];
    const float* q_g   = (const float*)d_in[3];
    const float* q_b   = (const float*)d_in[4];
    const float* W_dkv = (const float*)d_in[5];
    const float* W_ukv = (const float*)d_in[6];
    const float* kv_g  = (const float*)d_in[7];
    const float* kv_b  = (const float*)d_in[8];
    const float* W_o   = (const float*)d_in[9];

    char* ws = (char*)d_ws;
    size_t off = 0;
    bf16* Wo16   = (bf16*)(ws + off); off += (size_t)D_MODEL * D_MODEL * 2;
    bf16* Wt_dq  = (bf16*)(ws + off); off += (size_t)PROJ * D_MODEL * 2;
    bf16* Wt_dkv = (bf16*)(ws + off); off += (size_t)PROJ * D_MODEL * 2;
    bf16* Wt_uq  = (bf16*)(ws + off); off += (size_t)D_MODEL * PROJ * 2;
    bf16* Wt_ukv = (bf16*)(ws + off); off += (size_t)(2 * D_MODEL) * PROJ * 2;
    bf16* x16    = (bf16*)(ws + off); off += (size_t)TOK * D_MODEL * 2;
    bf16* cq     = (bf16*)(ws + off); off += (size_t)TOK * PROJ * 2;
    bf16* ckv    = (bf16*)(ws + off); off += (size_t)TOK * PROJ * 2;
    bf16* Qh     = (bf16*)(ws + off); off += (size_t)TOK * D_MODEL * 2;
    bf16* Kh     = (bf16*)(ws + off); off += (size_t)TOK * D_MODEL * 2;
    bf16* Vt     = (bf16*)(ws + off); off += (size_t)TOK * D_MODEL * 2;
    bf16* AT     = (bf16*)(ws + off); off += (size_t)TOK * D_MODEL * 2;

    prep_kernel<<<1344, 256, 0, stream>>>(
        W_o, x, W_dq, W_dkv, W_uq, W_ukv,
        Wo16, x16, Wt_dq, Wt_dkv, Wt_uq, Wt_ukv);

    gemm_ln_kernel<<<dim3(TOK / 16, 2), 256, 0, stream>>>(
        x16, Wt_dq, Wt_dkv, q_g, q_b, kv_g, kv_b, cq, ckv);

    gemm_qkv_kernel<<<768, 256, 0, stream>>>(cq, Wt_uq, ckv, Wt_ukv, Qh, Kh, Vt);

    attn_kernel<<<1024, 128, 0, stream>>>(Qh, Kh, Vt, AT);

    gemm_o_kernel<<<dim3(TOK / 64, D_MODEL / 128), 256, 0, stream>>>(
        AT, Wo16, (float*)d_out, TOK, D_MODEL, D_MODEL);
}

// Round 8
// 173.946 us; speedup vs baseline: 1.1632x; 1.1632x over previous
//
#include <hip/hip_runtime.h>

typedef __bf16 bf16;
typedef __bf16 bf16x4 __attribute__((ext_vector_type(4)));
typedef __bf16 bf16x8 __attribute__((ext_vector_type(8)));
typedef float f32x4 __attribute__((ext_vector_type(4)));

#define D_MODEL 1024
#define PROJ    256
#define SEQ     2048
#define BATCH   2
#define TOK     4096   // BATCH*SEQ
#define NH      16
#define DH      64
#define NEG_BIG (-1e30f)
#define QSCALE  0.18033688011112042f   // 0.125 * log2(e), folded into Qh

#if __has_builtin(__builtin_amdgcn_exp2f)
#define EXP2(x) __builtin_amdgcn_exp2f(x)
#else
#define EXP2(x) exp2f(x)
#endif

typedef __attribute__((address_space(3))) unsigned int  lds_u32;
typedef __attribute__((address_space(1))) unsigned int  glb_u32;

// async 16B/lane global->LDS (gfx950 global_load_lds_dwordx4).
__device__ __forceinline__ void gl2lds16(const void* gsrc, void* ldst) {
    __builtin_amdgcn_global_load_lds((const glb_u32*)gsrc, (lds_u32*)ldst, 16, 0, 0);
}

// counted waits (T4): never drain vmcnt to 0 inside the main loop.
#define VM_WAIT(N) asm volatile("s_waitcnt vmcnt(" #N ")" ::: "memory")
#define LGKM0      asm volatile("s_waitcnt lgkmcnt(0)" ::: "memory")
#define SCHEDB()   __builtin_amdgcn_sched_barrier(0)
#define SBAR()     __builtin_amdgcn_s_barrier()

// ---------------------------------------------------------------------------
// DPP 16-lane row sum (groups are contiguous 16-lane DPP rows).
template <int CTRL>
__device__ __forceinline__ float dppmov(float x) {
    int i = __builtin_bit_cast(int, x);
    i = __builtin_amdgcn_update_dpp(i, i, CTRL, 0xf, 0xf, false);
    return __builtin_bit_cast(float, i);
}
__device__ __forceinline__ float rowsum16(float v) {
    v += dppmov<0xB1>(v);
    v += dppmov<0x4E>(v);
    v += dppmov<0x141>(v);
    v += dppmov<0x140>(v);
    return v;
}

// ---------------------------------------------------------------------------
// Merged prep: blocks [0,320) LDS-tiled weight transposes; rest float4 copy.
__global__ __launch_bounds__(256) void prep_kernel(
    const float* __restrict__ W_o, const float* __restrict__ x,
    const float* __restrict__ W_dq, const float* __restrict__ W_dkv,
    const float* __restrict__ W_uq, const float* __restrict__ W_ukv,
    bf16* __restrict__ Wo16, bf16* __restrict__ x16,
    bf16* __restrict__ Wt_dq, bf16* __restrict__ Wt_dkv,
    bf16* __restrict__ Wt_uq, bf16* __restrict__ Wt_ukv) {
    if (blockIdx.x < 320) {
        __shared__ float tile[64][65];   // +1 pad: conflict-free transposed reads
        int t = blockIdx.x;
        const float* src; bf16* dst; int R, C;
        if (t < 64)       { src = W_dq;  dst = Wt_dq;  R = 1024; C = 256; }
        else if (t < 128) { src = W_dkv; dst = Wt_dkv; R = 1024; C = 256;  t -= 64; }
        else if (t < 192) { src = W_uq;  dst = Wt_uq;  R = 256;  C = 1024; t -= 128; }
        else              { src = W_ukv; dst = Wt_ukv; R = 256;  C = 2048; t -= 192; }
        const int tilesC = C >> 6;
        const int r0 = (t / tilesC) << 6;
        const int c0 = (t % tilesC) << 6;
        const int tr = threadIdx.x >> 6;   // 0..3
        const int tc = threadIdx.x & 63;
#pragma unroll
        for (int i = 0; i < 16; ++i)
            tile[tr * 16 + i][tc] = src[(size_t)(r0 + tr * 16 + i) * C + c0 + tc];
        __syncthreads();
#pragma unroll
        for (int i = 0; i < 16; ++i)
            dst[(size_t)(c0 + tr * 16 + i) * R + r0 + tc] =
                (bf16)tile[tc][tr * 16 + i];
    } else {
        const int NW = 262144;    // W_o float4 count
        const int NX = 1048576;   // x float4 count
        for (int i = (blockIdx.x - 320) * 256 + threadIdx.x; i < NW + NX;
             i += 1024 * 256) {
            if (i < NW) {
                float4 v = ((const float4*)W_o)[i];
                bf16x4 p;
                p[0] = (bf16)v.x; p[1] = (bf16)v.y;
                p[2] = (bf16)v.z; p[3] = (bf16)v.w;
                ((bf16x4*)Wo16)[i] = p;
            } else {
                int j = i - NW;
                float4 v = ((const float4*)x)[j];
                bf16x4 p;
                p[0] = (bf16)v.x; p[1] = (bf16)v.y;
                p[2] = (bf16)v.z; p[3] = (bf16)v.w;
                ((bf16x4*)x16)[j] = p;
            }
        }
    }
}

// ---------------------------------------------------------------------------
// Dual LN-GEMM v2. BM=32, N=256, BK=32, 8 waves (512 thr), 256 blocks
// (1 block/CU, 2 waves/SIMD). Wave (wr,wc) owns a 16-row x 64-col quadrant.
// Halves W panel traffic vs BM=16. 3-buffer, 1 barrier/step, counted vmcnt.
__global__ __launch_bounds__(512) void gemm_ln_kernel(
    const bf16* __restrict__ x16,
    const bf16* __restrict__ Wt_q, const bf16* __restrict__ Wt_kv,
    const float* __restrict__ q_g, const float* __restrict__ q_b,
    const float* __restrict__ kv_g, const float* __restrict__ kv_b,
    bf16* __restrict__ cq, bf16* __restrict__ ckv) {
    __shared__ alignas(16) bf16 xA[3][32 * 32];     // 3 x 2 KB
    __shared__ alignas(16) bf16 wB[3][256 * 32];    // 3 x 16 KB
    __shared__ float red1[8][16];
    __shared__ float red2[8][16];

    const int K = 1024;
    const bf16* Wt = blockIdx.y ? Wt_kv : Wt_q;
    const float* gamma = blockIdx.y ? kv_g : q_g;
    const float* beta  = blockIdx.y ? kv_b : q_b;
    bf16* out = blockIdx.y ? ckv : cq;

    const int m0 = blockIdx.x * 32;
    const int wv = threadIdx.x >> 6;      // 0..7
    const int lane = threadIdx.x & 63;
    const int g = lane >> 4;
    const int ln16 = lane & 15;
    const int wr = wv >> 2;               // 0..1: 16-row half
    const int wc = wv & 3;                // 0..3: 64-col quarter

    const int crow = lane >> 2;
    const int ckc = lane & 3;
    // x staged redundantly by all 8 waves (uniform per-wave load counts;
    // identical bytes -> benign duplicate LDS-DMA writes).
    const bf16* gx0 = x16 + (size_t)(m0 + crow) * K + ckc * 8;
    const bf16* gx1 = x16 + (size_t)(m0 + 16 + crow) * K + ckc * 8;
    const bf16* gw0 = Wt + (size_t)(32 * wv + crow) * K + ckc * 8;
    const bf16* gw1 = Wt + (size_t)(32 * wv + 16 + crow) * K + ckc * 8;

    f32x4 acc[4] = {};
    const int nst = K >> 5;          // 32 steps

    // prologue: stage steps 0,1 (4 loads/wave/step)
#pragma unroll
    for (int s = 0; s < 2; ++s) {
        gl2lds16(gx0 + s * 32, (char*)xA + s * 2048);
        gl2lds16(gx1 + s * 32, (char*)xA + s * 2048 + 1024);
        gl2lds16(gw0 + s * 32, (char*)wB + s * 16384 + wv * 2048);
        gl2lds16(gw1 + s * 32, (char*)wB + s * 16384 + wv * 2048 + 1024);
    }
    VM_WAIT(0); SCHEDB(); SBAR();

    for (int s = 0; s < nst; ++s) {
        if (s > 0) {
            if (s + 1 < nst) { VM_WAIT(4); } else { VM_WAIT(0); }
            SCHEDB(); SBAR();
        }
        if (s + 2 < nst) {
            const int b3 = (s + 2) % 3;
            const int k2 = (s + 2) * 32;
            gl2lds16(gx0 + k2, (char*)xA + b3 * 2048);
            gl2lds16(gx1 + k2, (char*)xA + b3 * 2048 + 1024);
            gl2lds16(gw0 + k2, (char*)wB + b3 * 16384 + wv * 2048);
            gl2lds16(gw1 + k2, (char*)wB + b3 * 16384 + wv * 2048 + 1024);
        }
        const bf16* cx = &xA[s % 3][0];
        const bf16* cw = &wB[s % 3][0];
        bf16x8 a = *(const bf16x8*)(cx + (wr * 16 + ln16) * 32 + g * 8);
        bf16x8 bb[4];
#pragma unroll
        for (int t = 0; t < 4; ++t)
            bb[t] = *(const bf16x8*)(cw + (wc * 64 + 16 * t + ln16) * 32 + g * 8);
        __builtin_amdgcn_s_setprio(1);
#pragma unroll
        for (int t = 0; t < 4; ++t)
            acc[t] = __builtin_amdgcn_mfma_f32_16x16x32_bf16(a, bb[t], acc[t], 0, 0, 0);
        __builtin_amdgcn_s_setprio(0);
    }

    // lane holds C rows m0+16wr+4g+r, cols 64wc+16t+ln16
    float s1[4], s2[4];
#pragma unroll
    for (int r = 0; r < 4; ++r) {
        float a = 0.f, b = 0.f;
#pragma unroll
        for (int t = 0; t < 4; ++t) { float v = acc[t][r]; a += v; b += v * v; }
        s1[r] = rowsum16(a); s2[r] = rowsum16(b);
    }
    if (ln16 == 0) {
#pragma unroll
        for (int r = 0; r < 4; ++r) {
            red1[wv][g * 4 + r] = s1[r];
            red2[wv][g * 4 + r] = s2[r];
        }
    }
    __syncthreads();
#pragma unroll
    for (int r = 0; r < 4; ++r) {
        int rl = g * 4 + r;
        float t1 = red1[wr * 4 + 0][rl] + red1[wr * 4 + 1][rl] +
                   red1[wr * 4 + 2][rl] + red1[wr * 4 + 3][rl];
        float t2 = red2[wr * 4 + 0][rl] + red2[wr * 4 + 1][rl] +
                   red2[wr * 4 + 2][rl] + red2[wr * 4 + 3][rl];
        float mu = t1 * (1.0f / 256.0f);
        float var = t2 * (1.0f / 256.0f) - mu * mu;
        float rs = rsqrtf(var + 1e-5f);
        int row = m0 + wr * 16 + rl;
#pragma unroll
        for (int t = 0; t < 4; ++t) {
            int col = wc * 64 + 16 * t + ln16;
            float v = (acc[t][r] - mu) * rs * gamma[col] + beta[col];
            out[(size_t)row * PROJ + col] = (bf16)v;
        }
    }
}

// ---------------------------------------------------------------------------
// 128x128 GEMM body, BK=32, 4 waves. 3-buffer, 1 barrier/step.
__device__ __forceinline__ void gemm_body128(
    const bf16* __restrict__ A, const bf16* __restrict__ Bt,
    bf16* __restrict__ C, bf16* __restrict__ C2, int K,
    int bx, int by, int mode, bf16* tA, bf16* tB) {
    // tA,tB: [3][128*32] bf16 (3 x 8 KB each)
    const int w = threadIdx.x >> 6;
    const int lane = threadIdx.x & 63;
    const int g = lane >> 4;
    const int ln16 = lane & 15;
    const int wr = w >> 1;
    const int wc = w & 1;

    const int m0 = bx * 128;
    const int n0 = by * 128;

    const int crow = lane >> 2;
    const int ckc = lane & 3;
    const bf16* gA0 = A  + (size_t)(m0 + 32 * w + crow) * K + ckc * 8;
    const bf16* gA1 = gA0 + (size_t)16 * K;
    const bf16* gB0 = Bt + (size_t)(n0 + 32 * w + crow) * K + ckc * 8;
    const bf16* gB1 = gB0 + (size_t)16 * K;

    f32x4 acc[4][4] = {};
    const int nst = K >> 5;

    // prologue: stage steps 0,1
#pragma unroll
    for (int s = 0; s < 2; ++s) {
        gl2lds16(gA0 + s * 32, (char*)tA + s * 8192 + w * 2048);
        gl2lds16(gA1 + s * 32, (char*)tA + s * 8192 + w * 2048 + 1024);
        gl2lds16(gB0 + s * 32, (char*)tB + s * 8192 + w * 2048);
        gl2lds16(gB1 + s * 32, (char*)tB + s * 8192 + w * 2048 + 1024);
    }
    VM_WAIT(0); SCHEDB(); SBAR();

    for (int s = 0; s < nst; ++s) {
        if (s > 0) {
            if (s + 1 < nst) { VM_WAIT(4); } else { VM_WAIT(0); }
            SCHEDB(); SBAR();
        }
        if (s + 2 < nst) {
            const int b3 = (s + 2) % 3;
            const int k2 = (s + 2) * 32;
            gl2lds16(gA0 + k2, (char*)tA + b3 * 8192 + w * 2048);
            gl2lds16(gA1 + k2, (char*)tA + b3 * 8192 + w * 2048 + 1024);
            gl2lds16(gB0 + k2, (char*)tB + b3 * 8192 + w * 2048);
            gl2lds16(gB1 + k2, (char*)tB + b3 * 8192 + w * 2048 + 1024);
        }
        const bf16* cA = tA + (s % 3) * 4096;   // elements
        const bf16* cB = tB + (s % 3) * 4096;

        bf16x8 af[4], bfr[4];
#pragma unroll
        for (int q = 0; q < 4; ++q)
            af[q] = *(const bf16x8*)(cA + (wr * 64 + q * 16 + ln16) * 32 + g * 8);
#pragma unroll
        for (int t = 0; t < 4; ++t)
            bfr[t] = *(const bf16x8*)(cB + (wc * 64 + t * 16 + ln16) * 32 + g * 8);
        __builtin_amdgcn_s_setprio(1);
#pragma unroll
        for (int q = 0; q < 4; ++q)
#pragma unroll
            for (int t = 0; t < 4; ++t)
                acc[q][t] = __builtin_amdgcn_mfma_f32_16x16x32_bf16(
                    af[q], bfr[t], acc[q][t], 0, 0, 0);
        __builtin_amdgcn_s_setprio(0);
    }

#pragma unroll
    for (int q = 0; q < 4; ++q)
#pragma unroll
        for (int t = 0; t < 4; ++t) {
            const int col = n0 + wc * 64 + t * 16 + ln16;
            const int tok0 = m0 + wr * 64 + q * 16 + g * 4;
            if (mode == 2 && col >= 1024) {
                int cc = col - 1024;
                int h = cc >> 6, d = cc & 63;
                int b = tok0 >> 11, sq = tok0 & 2047;
                bf16x4 pk;
#pragma unroll
                for (int r = 0; r < 4; ++r) pk[r] = (bf16)acc[q][t][r];
                *(bf16x4*)(C2 + ((size_t)((b * 16 + h) * 64 + d) * SEQ + sq)) = pk;
            } else {
#pragma unroll
                for (int r = 0; r < 4; ++r) {
                    int row = tok0 + r;
                    float v = acc[q][t][r];
                    if (mode == 1) v *= QSCALE;
                    int h = col >> 6, d = col & 63;
                    int b = row >> 11, sq = row & 2047;
                    C[((size_t)((b * 16 + h) * 2048 + sq)) * 64 + d] = (bf16)v;
                }
            }
        }
}

// Merged Q-proj + KV-proj: blocks [0,256) = Q (32x8), [256,768) = KV (32x16).
__global__ __launch_bounds__(256) void gemm_qkv_kernel(
    const bf16* __restrict__ cq, const bf16* __restrict__ Wt_uq,
    const bf16* __restrict__ ckv, const bf16* __restrict__ Wt_ukv,
    bf16* __restrict__ Qh, bf16* __restrict__ Kh, bf16* __restrict__ Vt) {
    __shared__ alignas(16) bf16 tA[3][128 * 32];
    __shared__ alignas(16) bf16 tB[3][128 * 32];
    const int i = blockIdx.x;
    if (i < 256) {
        gemm_body128(cq, Wt_uq, Qh, nullptr, PROJ,
                     i >> 3, i & 7, 1, &tA[0][0], &tB[0][0]);
    } else {
        const int j = i - 256;
        gemm_body128(ckv, Wt_ukv, Kh, Vt, PROJ,
                     j >> 4, j & 15, 2, &tA[0][0], &tB[0][0]);
    }
}

// ---------------------------------------------------------------------------
// 64x128 GEMM body, BK=32, 4 waves. 3-buffer, 1 barrier/step.
__device__ __forceinline__ void gemm_body(
    const bf16* __restrict__ A, const bf16* __restrict__ Bt,
    float* __restrict__ C, int N, int K,
    int bx, int by, bf16* tA, bf16* tB) {
    const int w = threadIdx.x >> 6;
    const int lane = threadIdx.x & 63;
    const int g = lane >> 4;
    const int ln16 = lane & 15;
    const int wr = w >> 1;
    const int wc = w & 1;

    const int m0 = bx * 64;
    const int n0 = by * 128;

    const int crow = lane >> 2;
    const int ckc = lane & 3;
    const bf16* gA  = A  + (size_t)(m0 + w * 16 + crow) * K + ckc * 8;
    const bf16* gB0 = Bt + (size_t)(n0 + w * 16 + crow) * K + ckc * 8;
    const bf16* gB1 = Bt + (size_t)(n0 + 64 + w * 16 + crow) * K + ckc * 8;

    f32x4 acc[2][4] = {};
    const int nst = K >> 5;

    // prologue: stage steps 0,1
#pragma unroll
    for (int s = 0; s < 2; ++s) {
        gl2lds16(gA + s * 32, (char*)tA + s * 4096 + w * 1024);
        gl2lds16(gB0 + s * 32, (char*)tB + s * 8192 + w * 1024);
        gl2lds16(gB1 + s * 32, (char*)tB + s * 8192 + 4096 + w * 1024);
    }
    VM_WAIT(0); SCHEDB(); SBAR();

    for (int s = 0; s < nst; ++s) {
        if (s > 0) {
            if (s + 1 < nst) { VM_WAIT(3); } else { VM_WAIT(0); }
            SCHEDB(); SBAR();
        }
        if (s + 2 < nst) {
            const int b3 = (s + 2) % 3;
            const int k2 = (s + 2) * 32;
            gl2lds16(gA + k2, (char*)tA + b3 * 4096 + w * 1024);
            gl2lds16(gB0 + k2, (char*)tB + b3 * 8192 + w * 1024);
            gl2lds16(gB1 + k2, (char*)tB + b3 * 8192 + 4096 + w * 1024);
        }
        const bf16* cA = tA + (s % 3) * 2048;   // elements
        const bf16* cB = tB + (s % 3) * 4096;

        bf16x8 af[2], bfr[4];
#pragma unroll
        for (int q = 0; q < 2; ++q)
            af[q] = *(const bf16x8*)(cA + (wr * 32 + q * 16 + ln16) * 32 + g * 8);
#pragma unroll
        for (int t = 0; t < 4; ++t)
            bfr[t] = *(const bf16x8*)(cB + (wc * 64 + t * 16 + ln16) * 32 + g * 8);
        __builtin_amdgcn_s_setprio(1);
#pragma unroll
        for (int q = 0; q < 2; ++q)
#pragma unroll
            for (int t = 0; t < 4; ++t)
                acc[q][t] = __builtin_amdgcn_mfma_f32_16x16x32_bf16(
                    af[q], bfr[t], acc[q][t], 0, 0, 0);
        __builtin_amdgcn_s_setprio(0);
    }

#pragma unroll
    for (int q = 0; q < 2; ++q)
#pragma unroll
        for (int t = 0; t < 4; ++t) {
            const int col = n0 + wc * 64 + t * 16 + ln16;
            const int tok0 = m0 + wr * 32 + q * 16 + g * 4;
#pragma unroll
            for (int r = 0; r < 4; ++r)
                C[(size_t)(tok0 + r) * N + col] = acc[q][t][r];
        }
}

// O-projection (fp32 out)
__global__ __launch_bounds__(256) void gemm_o_kernel(
    const bf16* __restrict__ A, const bf16* __restrict__ Bt,
    float* __restrict__ C, int M, int N, int K) {
    __shared__ alignas(16) bf16 tA[3][64 * 32];
    __shared__ alignas(16) bf16 tB[3][128 * 32];
    gemm_body(A, Bt, C, N, K, blockIdx.x, blockIdx.y, &tA[0][0], &tB[0][0]);
}

// ---------------------------------------------------------------------------
// Flash attention v9: best-measured geometry (1024 blocks x 256 thr, 4 waves
// x 16 q-rows, ~4 blocks/CU = 4 waves/SIMD, heavy-first backfill) + the
// counted-vmcnt skeleton: per wave 4 staging loads/tile (2 K + 2 V), prefetch
// distance 2, VM_WAIT(4) top rendezvous, LGKM0+SBAR before overwrite-stage.
// K and V both in LDS via coalesced gl2lds (V-direct refuted in r7).
// Swizzle: rows are 128B = 8 slots of 16B; chunk c of row r stored at slot
// c ^ f(r), f(r) = (r&3)|(((r>>3)&1)<<2), applied on the global src address.
__device__ __forceinline__ void qk_exp_pack(
    int k0, int q, bool masked, int g, int ln16,
    bf16x8 aq0, bf16x8 aq1, const bf16x8* Kf,
    bf16x8& P1, bf16x8& P2) {
    f32x4 sc[4];
    __builtin_amdgcn_s_setprio(1);
#pragma unroll
    for (int c = 0; c < 4; ++c) {
        f32x4 z = {};
        z = __builtin_amdgcn_mfma_f32_16x16x32_bf16(Kf[2 * c], aq0, z, 0, 0, 0);
        z = __builtin_amdgcn_mfma_f32_16x16x32_bf16(Kf[2 * c + 1], aq1, z, 0, 0, 0);
        sc[c] = z;
    }
    __builtin_amdgcn_s_setprio(0);
    if (masked) {
        const int kb = k0 + 8 * g;
#pragma unroll
        for (int c = 0; c < 4; ++c)
#pragma unroll
            for (int r = 0; r < 4; ++r) {
                int kcol = kb + (c & 1) * 4 + r + ((c >> 1) << 5);
                if (kcol > q) sc[c][r] = NEG_BIG;
            }
    }
#pragma unroll
    for (int c = 0; c < 4; ++c)
#pragma unroll
        for (int r = 0; r < 4; ++r) sc[c][r] = EXP2(sc[c][r]);
#pragma unroll
    for (int r = 0; r < 4; ++r) {
        P1[r] = (bf16)sc[0][r]; P1[4 + r] = (bf16)sc[1][r];
        P2[r] = (bf16)sc[2][r]; P2[4 + r] = (bf16)sc[3][r];
    }
}

__device__ __forceinline__ void pv_accum(
    bf16x8 P1, bf16x8 P2, const bf16x8* Vf, bf16x8 vones,
    f32x4* o, f32x4& oli) {
    __builtin_amdgcn_s_setprio(1);
#pragma unroll
    for (int t = 0; t < 4; ++t) {
        o[t] = __builtin_amdgcn_mfma_f32_16x16x32_bf16(Vf[2 * t], P1, o[t], 0, 0, 0);
        o[t] = __builtin_amdgcn_mfma_f32_16x16x32_bf16(Vf[2 * t + 1], P2, o[t], 0, 0, 0);
    }
    // li[q] = sum_k P[k][q] on the MFMA pipe (all output rows identical)
    oli = __builtin_amdgcn_mfma_f32_16x16x32_bf16(vones, P1, oli, 0, 0, 0);
    oli = __builtin_amdgcn_mfma_f32_16x16x32_bf16(vones, P2, oli, 0, 0, 0);
    __builtin_amdgcn_s_setprio(0);
}

__global__ __launch_bounds__(256) void attn_kernel(
    const bf16* __restrict__ Qh, const bf16* __restrict__ Kh,
    const bf16* __restrict__ Vt, bf16* __restrict__ AT) {
    __shared__ alignas(128) bf16 kbuf[2][64 * 64];   // [buf][k][d], swizzled
    __shared__ alignas(128) bf16 vbuf[2][64 * 64];   // [buf][d][k], swizzled

    const int lane = threadIdx.x & 63;
    const int g = lane >> 4;
    const int ln16 = lane & 15;
    const int wv = threadIdx.x >> 6;             // 0..3

    const int bh = blockIdx.x & 31;
    const int qsuper = 31 - (blockIdx.x >> 5);   // heavy-first
    const int nt = qsuper + 1;
    const int qb = qsuper * 64 + wv * 16;        // this wave's 16 q-rows
    const int q = qb + ln16;

    const bf16* Kbh = Kh + (size_t)bh * SEQ * DH;
    const bf16* Vbh = Vt + (size_t)bh * DH * SEQ;

    // ---- staging: wave wv stages K rows / V d-rows [16wv, 16wv+16), 2+2 instrs
    const int rho = lane >> 3;
    const int sl  = lane & 7;
    int kofs[2];
    size_t vofs[2];
#pragma unroll
    for (int i = 0; i < 2; ++i) {
        const int row = 16 * wv + 8 * i + rho;
        const int c = sl ^ ((rho & 3) | ((i & 1) << 2));  // = sl ^ f(row)
        kofs[i] = row * 64 + c * 8;
        vofs[i] = (size_t)row * SEQ + c * 8;
    }

    // ---- loop-invariant swizzled fragment-read byte offsets (within a buf)
    const int row_base = ((ln16 & 12) << 1) + (ln16 & 3);
    int kro[4], vro[4];
#pragma unroll
    for (int c = 0; c < 4; ++c) {
        const int row = row_base + (c & 1) * 4 + ((c >> 1) << 5);
        const int fr = (row & 3) | (((row >> 3) & 1) << 2);
        kro[c] = row * 128 + (g ^ fr) * 16;
    }
#pragma unroll
    for (int t = 0; t < 4; ++t) {
        const int d = 16 * t + ln16;
        const int fd = (d & 3) | (((d >> 3) & 1) << 2);
        vro[t] = d * 128 + (g ^ fd) * 16;
    }

    // Q fragments (issued before prologue VM_WAIT(0), retired there)
    const bf16* qp = Qh + ((size_t)bh * SEQ + q) * DH + g * 8;
    bf16x8 aq0 = *(const bf16x8*)qp, aq1 = *(const bf16x8*)(qp + 32);

    bf16x8 vones;
#pragma unroll
    for (int i = 0; i < 8; ++i) vones[i] = (bf16)1.0f;

    f32x4 o[4] = {};
    f32x4 oli = {};

    // prologue: stage tile 0 -> buf0, tile min(1,nt-1) -> buf1
    {
        const int t1 = (nt > 1) ? 1 : 0;
#pragma unroll
        for (int i = 0; i < 2; ++i) {
            gl2lds16(Kbh + kofs[i], (char*)kbuf + wv * 2048 + i * 1024);
            gl2lds16(Vbh + vofs[i], (char*)vbuf + wv * 2048 + i * 1024);
        }
#pragma unroll
        for (int i = 0; i < 2; ++i) {
            gl2lds16(Kbh + (size_t)t1 * 64 * 64 + kofs[i],
                     (char*)kbuf + 8192 + wv * 2048 + i * 1024);
            gl2lds16(Vbh + vofs[i] + (size_t)t1 * 64,
                     (char*)vbuf + 8192 + wv * 2048 + i * 1024);
        }
    }
    VM_WAIT(0); SCHEDB(); SBAR();

    for (int kt = 0; kt < nt; ++kt) {
        if (kt > 0) {
            if (kt + 1 < nt) { VM_WAIT(4); } else { VM_WAIT(0); }
            SCHEDB(); SBAR();
        }
        const char* kb = (const char*)kbuf + (kt & 1) * 8192;
        const char* vb = (const char*)vbuf + (kt & 1) * 8192;
        bf16x8 Kf[8], Vf[8];
#pragma unroll
        for (int c = 0; c < 4; ++c) {
            Kf[2 * c]     = *(const bf16x8*)(kb + kro[c]);
            Kf[2 * c + 1] = *(const bf16x8*)(kb + (kro[c] ^ 64));
        }
#pragma unroll
        for (int t = 0; t < 4; ++t) {
            Vf[2 * t]     = *(const bf16x8*)(vb + vro[t]);
            Vf[2 * t + 1] = *(const bf16x8*)(vb + (vro[t] ^ 64));
        }
        LGKM0; SCHEDB(); SBAR();     // all waves done reading buf[kt&1]
        if (kt + 2 < nt) {
            const size_t k0n = (size_t)(kt + 2) * 64;
            char* kd = (char*)kbuf + (kt & 1) * 8192 + wv * 2048;
            char* vd = (char*)vbuf + (kt & 1) * 8192 + wv * 2048;
#pragma unroll
            for (int i = 0; i < 2; ++i) {
                gl2lds16(Kbh + k0n * 64 + kofs[i], kd + i * 1024);
                gl2lds16(Vbh + vofs[i] + k0n, vd + i * 1024);
            }
        }

        bf16x8 P1, P2;
        qk_exp_pack(kt * 64, q, kt == qsuper, g, ln16, aq0, aq1, Kf, P1, P2);
        pv_accum(P1, P2, Vf, vones, o, oli);
        // no trailing barrier: next-iter top {VM_WAIT, SBAR} is the rendezvous
    }

    // epilogue: oli rows all identical = li[q]; no loads outstanding here
    // (last iteration's top wait was VM_WAIT(0) and it issued no stages)
    const float inv = 1.0f / oli[0];
    const int b = bh >> 4, h = bh & 15;
    const size_t tok = (size_t)(b * SEQ + q) * D_MODEL + h * DH;
#pragma unroll
    for (int t = 0; t < 4; ++t) {
        bf16x4 pk;
#pragma unroll
        for (int r = 0; r < 4; ++r) pk[r] = (bf16)(o[t][r] * inv);
        *(bf16x4*)(AT + tok + 16 * t + 4 * g) = pk;
    }
}

// ---------------------------------------------------------------------------
extern "C" void kernel_launch(void* const* d_in, const int* in_sizes, int n_in,
                              void* d_out, int out_size, void* d_ws, size_t ws_size,
                              hipStream_t stream) {
    const float* x     = (const float*)d_in[0];
    const float* W_dq  = (const float*)d_in[1];
    const float* W_uq  = (const float*)d_in[2];
    const float* q_g   = (const float*)d_in[3];
    const float* q_b   = (const float*)d_in[4];
    const float* W_dkv = (const float*)d_in[5];
    const float* W_ukv = (const float*)d_in[6];
    const float* kv_g  = (const float*)d_in[7];
    const float* kv_b  = (const float*)d_in[8];
    const float* W_o   = (const float*)d_in[9];

    char* ws = (char*)d_ws;
    size_t off = 0;
    bf16* Wo16   = (bf16*)(ws + off); off += (size_t)D_MODEL * D_MODEL * 2;
    bf16* Wt_dq  = (bf16*)(ws + off); off += (size_t)PROJ * D_MODEL * 2;
    bf16* Wt_dkv = (bf16*)(ws + off); off += (size_t)PROJ * D_MODEL * 2;
    bf16* Wt_uq  = (bf16*)(ws + off); off += (size_t)D_MODEL * PROJ * 2;
    bf16* Wt_ukv = (bf16*)(ws + off); off += (size_t)(2 * D_MODEL) * PROJ * 2;
    bf16* x16    = (bf16*)(ws + off); off += (size_t)TOK * D_MODEL * 2;
    bf16* cq     = (bf16*)(ws + off); off += (size_t)TOK * PROJ * 2;
    bf16* ckv    = (bf16*)(ws + off); off += (size_t)TOK * PROJ * 2;
    bf16* Qh     = (bf16*)(ws + off); off += (size_t)TOK * D_MODEL * 2;
    bf16* Kh     = (bf16*)(ws + off); off += (size_t)TOK * D_MODEL * 2;
    bf16* Vt     = (bf16*)(ws + off); off += (size_t)TOK * D_MODEL * 2;
    bf16* AT     = (bf16*)(ws + off); off += (size_t)TOK * D_MODEL * 2;

    prep_kernel<<<1344, 256, 0, stream>>>(
        W_o, x, W_dq, W_dkv, W_uq, W_ukv,
        Wo16, x16, Wt_dq, Wt_dkv, Wt_uq, Wt_ukv);

    gemm_ln_kernel<<<dim3(TOK / 32, 2), 512, 0, stream>>>(
        x16, Wt_dq, Wt_dkv, q_g, q_b, kv_g, kv_b, cq, ckv);

    gemm_qkv_kernel<<<768, 256, 0, stream>>>(cq, Wt_uq, ckv, Wt_ukv, Qh, Kh, Vt);

    attn_kernel<<<1024, 256, 0, stream>>>(Qh, Kh, Vt, AT);

    gemm_o_kernel<<<dim3(TOK / 64, D_MODEL / 128), 256, 0, stream>>>(
        AT, Wo16, (float*)d_out, TOK, D_MODEL, D_MODEL);
}